// Round 1
// baseline (178.719 us; speedup 1.0000x reference)
//
#include <hip/hip_runtime.h>
#include <hip/hip_bf16.h>

// Problem constants (fixed by setup_inputs): B=16, K=512, D=256, T=4096, fp32 in/out.
#define BK 512      // phonemes
#define BD 256      // feature dim
#define BT 4096     // frames
#define TT 256      // t-tile per block (== blockDim.x)
#define W  32       // softmax window (centers spacing ~8 frames; +/-16 indices ~ +/-128 frames)
#define DSPLIT 4    // split the d-loop across blocks for occupancy (4 blocks/CU)

__global__ __launch_bounds__(256)
void upsampler_kernel(const float* __restrict__ durations,  // (B,K)
                      const float* __restrict__ phoneme,    // (B,D,K)
                      const float* __restrict__ frame,      // (B,D,T)
                      float* __restrict__ out)              // (B,D,T)
{
    const int b   = blockIdx.x;     // batch
    const int tt  = blockIdx.y;     // t-tile index
    const int ds  = blockIdx.z;     // d-split index
    const int tid = threadIdx.x;    // 0..255

    __shared__ float s_c[BK];       // phoneme centers for this batch
    __shared__ float s_ph[BK];      // one phoneme row (d fixed)
    __shared__ float s_wsum[4];     // per-wave pair-sum totals for the scan

    // ---------------- centers = cumsum(dur) - 0.5*dur (recomputed per block; cheap) ----
    const float d0v = durations[b * BK + 2 * tid];
    const float d1v = durations[b * BK + 2 * tid + 1];
    const float s   = d0v + d1v;

    // inclusive scan of pair-sums within each wave (64 lanes)
    float scan = s;
    #pragma unroll
    for (int off = 1; off < 64; off <<= 1) {
        float other = __shfl_up(scan, off, 64);
        if ((tid & 63) >= off) scan += other;
    }
    if ((tid & 63) == 63) s_wsum[tid >> 6] = scan;
    __syncthreads();
    float woff = 0.f;
    const int wv = tid >> 6;
    for (int i = 0; i < wv; ++i) woff += s_wsum[i];
    const float acc1 = woff + scan;            // inclusive cumsum at element 2*tid+1
    s_c[2 * tid]     = (acc1 - d1v) - 0.5f * d0v;
    s_c[2 * tid + 1] = acc1 - 0.5f * d1v;
    __syncthreads();

    // ---------------- per-thread windowed softmax over centers ----------------
    const float tc = (float)(tt * TT + tid) + 0.5f;   // frame center

    // lower_bound: count of centers < tc (centers strictly increasing)
    int pos = 0;
    #pragma unroll
    for (int st = 256; st > 0; st >>= 1) {
        int np = pos + st;
        if (np <= BK && s_c[np - 1] < tc) pos = np;
    }
    int wstart = (pos - W / 2) & ~3;                  // align to float4
    wstart = max(0, min(BK - W, wstart));

    float e[W];
    float m = -1e30f;
    #pragma unroll
    for (int j = 0; j < W; ++j) {
        float dd = tc - s_c[wstart + j];
        e[j] = -dd * dd;
        m = fmaxf(m, e[j]);
    }
    float sum = 0.f;
    #pragma unroll
    for (int j = 0; j < W; ++j) { e[j] = __expf(e[j] - m); sum += e[j]; }
    const float inv = 1.0f / sum;
    #pragma unroll
    for (int j = 0; j < W; ++j) e[j] *= inv;

    // ---------------- weighted gather over d rows ----------------
    const int dlo = ds * (BD / DSPLIT);
    const int dhi = dlo + (BD / DSPLIT);
    const float* phb  = phoneme + (size_t)b * BD * BK;
    const float* frb  = frame   + (size_t)b * BD * BT + (size_t)tt * TT;
    float*       outb = out     + (size_t)b * BD * BT + (size_t)tt * TT;

    for (int d = dlo; d < dhi; ++d) {
        __syncthreads();   // protect previous iteration's s_ph reads
        // stage phoneme row (512 floats) with 256 threads
        ((float2*)s_ph)[tid] = ((const float2*)(phb + (size_t)d * BK))[tid];
        __syncthreads();

        const float4* sp4 = (const float4*)(s_ph + wstart);  // wstart is 4-aligned
        float a0 = 0.f, a1 = 0.f, a2 = 0.f, a3 = 0.f;
        #pragma unroll
        for (int jj = 0; jj < W / 4; ++jj) {
            float4 p = sp4[jj];
            a0 += e[4 * jj + 0] * p.x;
            a1 += e[4 * jj + 1] * p.y;
            a2 += e[4 * jj + 2] * p.z;
            a3 += e[4 * jj + 3] * p.w;
        }
        const size_t idx = (size_t)d * BT + tid;
        outb[idx] = (a0 + a1) + (a2 + a3) + frb[idx];
    }
}

extern "C" void kernel_launch(void* const* d_in, const int* in_sizes, int n_in,
                              void* d_out, int out_size, void* d_ws, size_t ws_size,
                              hipStream_t stream) {
    const float* durations = (const float*)d_in[0];   // (16, 512)
    const float* phoneme   = (const float*)d_in[1];   // (16, 256, 512)
    const float* frame     = (const float*)d_in[2];   // (16, 256, 4096)
    float* out = (float*)d_out;                       // (16, 256, 4096)

    dim3 grid(16, BT / TT, DSPLIT);   // (B, T/256, 4) = 1024 blocks
    upsampler_kernel<<<grid, 256, 0, stream>>>(durations, phoneme, frame, out);
}